// Round 15
// baseline (103.541 us; speedup 1.0000x reference)
//
#include <hip/hip_runtime.h>

// Separable 3D Gaussian blur (sigma=1, truncate=3 -> 7 taps), SAME zero padding.
// (N=2, D=160, H=160, W=160, C=4) float32 == float4 over C.
// Round 15 = R11 (best: 79.2us) + ONE change: gap-swizzled LDS layout.
//   Column cc stored at cc + (cc>>3) (one float4 gap every 8 columns) in both
//   raw and wb. Kills the 4-way bank conflict in the W-phase (8 workers/row
//   at 4-f4 stride hit banks {0,16,0,16,...}; with gaps they hit
//   {0,4,1,5,2,6,3,7}*4 -- all distinct). Same fix applies to wb writes.
//   H-reads become <=2-way (free per m136).
// Unchanged from R11: tile 16x32, CHUNK=10, 1600 blocks, XCD-chunked swizzle,
// single-buffered f32 raw+wb, 176 W-workers x (10 b128 reads -> 4 outputs),
// H-pairs with dual 7-deep D-rings, prefetch-1, 2 lgkmcnt-only barriers,
// launch_bounds(256,4). Spill canary: WRITE_SIZE must stay ~134MB.

#define THT 16
#define TWT 32
#define CHUNK 10
#define DIM 160
#define SLICE (DIM * DIM)
#define RAWN (22 * 38)
#define NBLK 1600          // 2*10*5*16 = 8 XCDs x 200

// gap-swizzled row lengths: raw cols 0..37 -> 0..41 (len 43 w/ pad);
// wb cols 0..31 -> 0..34 (len 37 w/ pad)
#define RAWLD 43
#define WBLD 37
#define GAP(c) ((c) + ((c) >> 3))

#define W0 0.004433048f
#define W1 0.054005582f
#define W2 0.242036229f
#define W3 0.399050300f

__device__ __forceinline__ float4 blur7(float4 a0, float4 a1, float4 a2, float4 a3,
                                        float4 a4, float4 a5, float4 a6) {
    float4 r;
    r.x = W0 * (a0.x + a6.x) + W1 * (a1.x + a5.x) + W2 * (a2.x + a4.x) + W3 * a3.x;
    r.y = W0 * (a0.y + a6.y) + W1 * (a1.y + a5.y) + W2 * (a2.y + a4.y) + W3 * a3.y;
    r.z = W0 * (a0.z + a6.z) + W1 * (a1.z + a5.z) + W2 * (a2.z + a4.z) + W3 * a3.z;
    r.w = W0 * (a0.w + a6.w) + W1 * (a1.w + a5.w) + W2 * (a2.w + a4.w) + W3 * a3.w;
    return r;
}

// Workgroup barrier with LDS visibility but NO vmcnt(0) drain -> prefetched
// global loads stay in flight across it.
__device__ __forceinline__ void lds_barrier() {
    asm volatile("s_waitcnt lgkmcnt(0)" ::: "memory");
    __builtin_amdgcn_s_barrier();
}

__global__ __launch_bounds__(256, 4)
void gauss3d_fused(const float4* __restrict__ in, float4* __restrict__ out) {
    // XCD-chunked bijective swizzle: 1600 = 8 * 200 exactly.
    int work = (blockIdx.x & 7) * (NBLK / 8) + (blockIdx.x >> 3);
    const int tw    = work % (DIM / TWT);   work /= (DIM / TWT);   // 5
    const int th    = work % (DIM / THT);   work /= (DIM / THT);   // 10
    const int chunk = work % (DIM / CHUNK); work /= (DIM / CHUNK); // 16
    const int n     = work;                                        // 2

    const int h0 = th * THT;
    const int w0 = tw * TWT;
    const int d0 = chunk * CHUNK;

    __shared__ float4 raw[22][RAWLD];  // halo 22(H) x 38(W), gap-swizzled
    __shared__ float4 wb[22][WBLD];    // W-blurred 22 x 32, gap-swizzled

    const int tid = threadIdx.x;
    const size_t nbase = (size_t)n * DIM * SLICE;
    const float4 z = make_float4(0.f, 0.f, 0.f, 0.f);

    // ---- stage constants: 836 halo f4 over 256 threads (<=4 slots) ----
    int  soff[4], rbidx[4];
    bool sok[4];
    #pragma unroll
    for (int s = 0; s < 4; ++s) {
        const int i = tid + 256 * s;
        const bool has = (i < RAWN);
        const int rr = has ? (i / 38) : 0, cc = has ? (i % 38) : 0;
        const int gh = h0 + rr - 3, gw = w0 + cc - 3;
        const bool ok = has && gh >= 0 && gh < DIM && gw >= 0 && gw < DIM;
        soff[s]  = ok ? (gh * DIM + gw) : 0;
        sok[s]   = ok;
        rbidx[s] = rr * RAWLD + GAP(cc);
    }
    const bool shas3 = (tid + 768 < RAWN);

    // ---- W-blur workers: 176 = 22 rows x 8 groups of 4 cols ----
    const bool isW = (tid < 176);
    const int wr  = tid >> 3;        // 0..21
    const int wc0 = (tid & 7) * 4;   // 0,4,...,28

    // ---- H-blur: 256 threads = 8 H-pairs x 32 cols ----
    const int hp = tid >> 5;         // 0..7 -> output rows 2hp, 2hp+1
    const int lw = tid & 31;         // 0..31
    const int lwg = GAP(lw);         // gap-swizzled column for wb reads

    float4 pf0, pf1, pf2, pf3;
    float4 a0 = z, a1 = z, a2 = z, a3 = z, a4 = z, a5 = z, a6 = z;  // ring row 2hp
    float4 b0 = z, b1 = z, b2 = z, b3 = z, b4 = z, b5 = z, b6 = z;  // ring row 2hp+1

#define PREFETCH(DSL)                                                        \
    do {                                                                     \
        const int _d = (DSL);                                                \
        const bool _inr = (_d >= 0) && (_d < DIM);                           \
        const float4* _s = in + nbase + (size_t)(_inr ? _d : 0) * SLICE;     \
        pf0 = (_inr && sok[0]) ? _s[soff[0]] : z;                            \
        pf1 = (_inr && sok[1]) ? _s[soff[1]] : z;                            \
        pf2 = (_inr && sok[2]) ? _s[soff[2]] : z;                            \
        pf3 = (_inr && sok[3]) ? _s[soff[3]] : z;                            \
    } while (0)

    PREFETCH(d0 - 3);

    for (int din = d0 - 3; din <= d0 + CHUNK + 2; ++din) {
        // 1) commit prefetched slice into raw (prev W-blur reads of raw
        //    drained at previous iteration's barrier B -> single buf safe)
        {
            float4* rb = &raw[0][0];
            rb[rbidx[0]] = pf0;
            rb[rbidx[1]] = pf1;
            rb[rbidx[2]] = pf2;
            if (shas3) rb[rbidx[3]] = pf3;
        }

        // 2) issue next slice's loads; in flight across both barriers
        PREFETCH(din + 1);

        lds_barrier();  // A: raw visible; prev H-blur reads of wb drained

        // 3) W-blur: 176 workers, 10 gap-addressed raw reads -> 4 wb outputs
        if (isW) {
            const float4* rrow = &raw[wr][0];
            float4 rv0 = rrow[GAP(wc0 + 0)];
            float4 rv1 = rrow[GAP(wc0 + 1)];
            float4 rv2 = rrow[GAP(wc0 + 2)];
            float4 rv3 = rrow[GAP(wc0 + 3)];
            float4 rv4 = rrow[GAP(wc0 + 4)];
            float4 rv5 = rrow[GAP(wc0 + 5)];
            float4 rv6 = rrow[GAP(wc0 + 6)];
            float4 rv7 = rrow[GAP(wc0 + 7)];
            float4 rv8 = rrow[GAP(wc0 + 8)];
            float4 rv9 = rrow[GAP(wc0 + 9)];
            float4* wrow = &wb[wr][0];
            wrow[GAP(wc0 + 0)] = blur7(rv0, rv1, rv2, rv3, rv4, rv5, rv6);
            wrow[GAP(wc0 + 1)] = blur7(rv1, rv2, rv3, rv4, rv5, rv6, rv7);
            wrow[GAP(wc0 + 2)] = blur7(rv2, rv3, rv4, rv5, rv6, rv7, rv8);
            wrow[GAP(wc0 + 3)] = blur7(rv3, rv4, rv5, rv6, rv7, rv8, rv9);
        }

        lds_barrier();  // B: wb visible; raw reads drained (next top rewrites)

        // 4) H-blur pair: 8 wb reads -> 2 new ring values
        {
            float4 c0 = wb[2 * hp + 0][lwg];
            float4 c1 = wb[2 * hp + 1][lwg];
            float4 c2 = wb[2 * hp + 2][lwg];
            float4 c3 = wb[2 * hp + 3][lwg];
            float4 c4 = wb[2 * hp + 4][lwg];
            float4 c5 = wb[2 * hp + 5][lwg];
            float4 c6 = wb[2 * hp + 6][lwg];
            float4 c7 = wb[2 * hp + 7][lwg];
            float4 va = blur7(c0, c1, c2, c3, c4, c5, c6);
            float4 vb = blur7(c1, c2, c3, c4, c5, c6, c7);
            a0 = a1; a1 = a2; a2 = a3; a3 = a4; a4 = a5; a5 = a6; a6 = va;
            b0 = b1; b1 = b2; b2 = b3; b3 = b4; b4 = b5; b5 = b6; b6 = vb;
        }

        const int dout = din - 3;
        if (dout >= d0) {   // dout < d0+CHUNK by loop bound
            float4 oa = blur7(a0, a1, a2, a3, a4, a5, a6);
            float4 ob = blur7(b0, b1, b2, b3, b4, b5, b6);
            const size_t base = nbase + (size_t)dout * SLICE;
            out[base + (size_t)(h0 + 2 * hp + 0) * DIM + (w0 + lw)] = oa;
            out[base + (size_t)(h0 + 2 * hp + 1) * DIM + (w0 + lw)] = ob;
        }
    }
#undef PREFETCH
}

extern "C" void kernel_launch(void* const* d_in, const int* in_sizes, int n_in,
                              void* d_out, int out_size, void* d_ws, size_t ws_size,
                              hipStream_t stream) {
    const float4* in = (const float4*)d_in[0];
    float4* out = (float4*)d_out;
    gauss3d_fused<<<NBLK, 256, 0, stream>>>(in, out);
}